// Round 6
// baseline (396.314 us; speedup 1.0000x reference)
//
#include <hip/hip_runtime.h>

typedef unsigned short ushort_t;
typedef __attribute__((ext_vector_type(8))) short short8;
typedef __attribute__((ext_vector_type(4))) float f32x4;

#define HWp 12288      // 96*128
#define NB  16

// workspace byte offsets
#define OFF_WFRAG1 0        // bf16 [7 kb][6 mb][64 lane][8 j]  (c1: 96x224)
#define OFF_WFRAG2 43008    // bf16 [4 kb][5 mb][64 lane][8 j]  (pw: 80x128)
#define OFF_WF1T   63488    // f32 [2][64]
#define OFF_WF2T   64000    // f32 [64][32]
#define OFF_WDQ    72192    // f32 [128][9]
#define OFF_CORFLO 131072   // bf16 [16][128][12288]

__device__ __forceinline__ short f2bf(float f) {
  unsigned u = __builtin_bit_cast(unsigned, f);
  u = (u + 0x7FFFu + ((u >> 16) & 1u)) >> 16;   // RNE
  return (short)u;
}
__device__ __forceinline__ float bf2f(ushort_t u) {
  return __builtin_bit_cast(float, (unsigned)u << 16);
}
__device__ __forceinline__ int swz(int a16) { return a16 ^ ((a16 >> 2) & 3); }

__device__ __forceinline__ void gload_lds16(const void* g, void* l) {
  __builtin_amdgcn_global_load_lds(
      (const __attribute__((address_space(1))) unsigned*)g,
      (__attribute__((address_space(3))) unsigned*)l, 16, 0, 0);
}

// ---------------------------------------------------------------------------
// Kernel 0: fake-quant all weights; pack GEMM weights into MFMA A-fragment
// order (bf16); transpose flow weights; copy dw weights.
// ---------------------------------------------------------------------------
__global__ __launch_bounds__(1024) void quant_pack(
    const float* __restrict__ Wc1, const float* __restrict__ Wf1,
    const float* __restrict__ Wf2, const float* __restrict__ Wd,
    const float* __restrict__ Wp, char* __restrict__ ws)
{
  int t = blockIdx.x;
  const float* src; int n;
  if      (t == 0) { src = Wc1; n = 96*196; }
  else if (t == 1) { src = Wf1; n = 128; }
  else if (t == 2) { src = Wf2; n = 2048; }
  else if (t == 3) { src = Wd;  n = 1152; }
  else             { src = Wp;  n = 10240; }

  __shared__ float red[1024];
  float m = 0.f;
  for (int i = threadIdx.x; i < n; i += 1024) m = fmaxf(m, fabsf(src[i]));
  red[threadIdx.x] = m;
  __syncthreads();
  for (int s = 512; s > 0; s >>= 1) {
    if (threadIdx.x < s) red[threadIdx.x] = fmaxf(red[threadIdx.x], red[threadIdx.x + s]);
    __syncthreads();
  }
  float scale = fmaxf(red[0], 1e-8f) / 127.0f;

  if (t == 0) {
    short* dst = (short*)(ws + OFF_WFRAG1);
    for (int i = threadIdx.x; i < 21504; i += 1024) {
      int j = i & 7, lane = (i >> 3) & 63, rest = i >> 9;
      int mb = rest % 6, kb = rest / 6;
      int ch = mb*16 + (lane & 15);
      int k  = kb*32 + ((lane >> 4) << 3) + j;
      float v = 0.f;
      if (k < 196) {
        float q = rintf(src[ch*196 + k] / scale);
        v = fminf(fmaxf(q, -127.f), 127.f) * scale;
      }
      dst[i] = f2bf(v);
    }
  } else if (t == 4) {
    short* dst = (short*)(ws + OFF_WFRAG2);
    for (int i = threadIdx.x; i < 10240; i += 1024) {
      int j = i & 7, lane = (i >> 3) & 63, rest = i >> 9;
      int mb = rest % 5, kb = rest / 5;
      int ch = mb*16 + (lane & 15);
      int k  = kb*32 + ((lane >> 4) << 3) + j;
      float q = rintf(src[ch*128 + k] / scale);
      dst[i] = f2bf(fminf(fmaxf(q, -127.f), 127.f) * scale);
    }
  } else if (t == 1) {
    float* dst = (float*)(ws + OFF_WF1T);
    for (int i = threadIdx.x; i < 128; i += 1024) {
      int o = i >> 1, c = i & 1;
      float q = rintf(src[i] / scale);
      dst[c*64 + o] = fminf(fmaxf(q, -127.f), 127.f) * scale;
    }
  } else if (t == 2) {
    float* dst = (float*)(ws + OFF_WF2T);
    for (int i = threadIdx.x; i < 2048; i += 1024) {
      int o = i >> 6, c = i & 63;
      float q = rintf(src[i] / scale);
      dst[c*32 + o] = fminf(fmaxf(q, -127.f), 127.f) * scale;
    }
  } else {
    float* dst = (float*)(ws + OFF_WDQ);
    for (int i = threadIdx.x; i < 1152; i += 1024) {
      float q = rintf(src[i] / scale);
      dst[i] = fminf(fmaxf(q, -127.f), 127.f) * scale;
    }
  }
}

// ---------------------------------------------------------------------------
// Stage 1 (MFMA, global_load_lds staged, double-buffered):
// cor = relu(Wc1q[96x196] @ corr[196 x 128px]) per 128-px block.
// Per K-step: 32k x 128px fp32 tile (16.6 KB, rows padded per 2-k group to
// 1040 B to break lg-stride bank aliasing) staged by DMA; one __syncthreads
// per K-step (its vmcnt(0)+barrier is the 2-phase trailing wait).
// K tail (196..223) handled by clamped staging + in-register masking.
// ---------------------------------------------------------------------------
__global__ __launch_bounds__(256) void stage1_mfma(
    const float* __restrict__ corr, const float* __restrict__ bc1,
    char* __restrict__ ws)
{
  // [2 bufs][16 groups of 2 k-rows][260 dwords] (2*128 data + 4 pad)
  __shared__ float s_corr[2][16*260];
  const int t = threadIdx.x;
  const int wave = t >> 6, lane = t & 63;
  const int lg = (lane >> 4) & 3, lr = lane & 15;
  const int b = blockIdx.x / 96;
  const int px_base = (blockIdx.x % 96) * 128;
  const float* cbase = corr + (size_t)b * 196 * HWp;

  f32x4 acc[2][6];
#pragma unroll
  for (int f = 0; f < 2; f++)
#pragma unroll
    for (int mb = 0; mb < 6; mb++) acc[f][mb] = f32x4{0.f, 0.f, 0.f, 0.f};

  const short8* wf = (const short8*)(ws + OFF_WFRAG1);

  // staging geometry: u = i*256 + t (0..1023 16B-units per K-step)
  //   ktile = u>>5 (0..31), px4 = u&31, group g = u>>6 (wave-uniform), lane off
#define S1_STAGE(KB, BUF)                                                     \
  {                                                                           \
    _Pragma("unroll")                                                         \
    for (int i = 0; i < 4; i++) {                                             \
      int u = i*256 + t;                                                      \
      int ktile = u >> 5;                                                     \
      int kglob = (KB)*32 + ktile; if (kglob > 195) kglob = 195;              \
      int g = i*4 + wave;                                                     \
      gload_lds16(cbase + (size_t)kglob*HWp + px_base + (u & 31)*4,           \
                  &s_corr[BUF][g*260] + (u & 63)*4);                          \
    }                                                                         \
  }

  S1_STAGE(0, 0);

  for (int kb = 0; kb < 7; kb++) {
    const int cur = kb & 1;
    if (kb < 6) S1_STAGE(kb + 1, cur ^ 1);
    __syncthreads();   // vmcnt(0)+barrier: buf[cur] ready; buf[cur^1] readers done

    short8 aa[2];
#pragma unroll
    for (int f = 0; f < 2; f++) {
      int px = wave*32 + f*16 + lr;
#pragma unroll
      for (int j = 0; j < 8; j++) {
        // k = lg*8 + j ; dword addr = (lg*4 + (j>>1))*260 + (j&1)*128 + px
        float v = s_corr[cur][(lg*4 + (j >> 1))*260 + (j & 1)*128 + px];
        if (kb == 6) v = (lg == 0 && j < 4) ? v : 0.f;   // K tail mask
        aa[f][j] = f2bf(v);
      }
    }
#pragma unroll
    for (int mb = 0; mb < 6; mb++) {
      short8 w = wf[(kb*6 + mb)*64 + lane];
      acc[0][mb] = __builtin_amdgcn_mfma_f32_16x16x32_bf16(w, aa[0], acc[0][mb], 0, 0, 0);
      acc[1][mb] = __builtin_amdgcn_mfma_f32_16x16x32_bf16(w, aa[1], acc[1][mb], 0, 0, 0);
    }
  }

  ushort_t* cf = (ushort_t*)(ws + OFF_CORFLO) + (size_t)b*128*HWp;
#pragma unroll
  for (int f = 0; f < 2; f++) {
    int px = px_base + wave*32 + f*16 + lr;
#pragma unroll
    for (int mb = 0; mb < 6; mb++)
#pragma unroll
      for (int r = 0; r < 4; r++) {
        int ch = mb*16 + lg*4 + r;
        cf[(size_t)ch*HWp + px] = (ushort_t)f2bf(fmaxf(acc[f][mb][r] + bc1[ch], 0.f));
      }
  }
#undef S1_STAGE
}

// ---------------------------------------------------------------------------
// Flow path (scalar, cheap): relu(1x1 2->64) -> relu(1x1 64->32),
// writes channels 96..127 of cor_flo as bf16.
// ---------------------------------------------------------------------------
__global__ __launch_bounds__(256) void flow_path(
    const float* __restrict__ flow, const float* __restrict__ bf1,
    const float* __restrict__ bf2, char* __restrict__ ws)
{
  int pix = blockIdx.x * 256 + threadIdx.x;
  int b = pix / HWp, p = pix - b*HWp;
  const float* wf1t = (const float*)(ws + OFF_WF1T);
  const float* wf2t = (const float*)(ws + OFF_WF2T);
  float x0 = flow[(size_t)(b*2 + 0)*HWp + p];
  float x1 = flow[(size_t)(b*2 + 1)*HWp + p];
  float h[64];
#pragma unroll
  for (int o = 0; o < 64; o++)
    h[o] = fmaxf(bf1[o] + x0*wf1t[o] + x1*wf1t[64 + o], 0.f);
  float g[32];
#pragma unroll
  for (int o = 0; o < 32; o++) g[o] = bf2[o];
#pragma unroll
  for (int c = 0; c < 64; c++) {
    float a = h[c];
#pragma unroll
    for (int o = 0; o < 32; o++) g[o] += a * wf2t[c*32 + o];
  }
  ushort_t* dst = (ushort_t*)(ws + OFF_CORFLO) + ((size_t)b*128 + 96)*HWp + p;
#pragma unroll
  for (int o = 0; o < 32; o++)
    dst[(size_t)o*HWp] = (ushort_t)f2bf(fmaxf(g[o], 0.f));
}

// ---------------------------------------------------------------------------
// Stage 2 (MFMA, double-buffered inb): per 2-row x 128 tile, per 32-ch chunk:
//   STAGE(cb+1) issued at LOOP TOP (latency hides under ~900cy of dw VALU),
//   then dw 3x3 -> pack bf16 actc (swizzled) -> MFMA K-step.
// __syncthreads drains are free: staging issued one full dw-phase earlier.
// ---------------------------------------------------------------------------
__global__ __launch_bounds__(256) void stage2_mfma(
    const float* __restrict__ bp, const float* __restrict__ flow,
    const char* __restrict__ ws, float* __restrict__ out)
{
  __shared__ ushort_t inb[2][32*4*128];  // 64 KB dbuf: [ch][ry 0..3][x]
  __shared__ ushort_t actc[4*256*8];     // 16 KB: [kg][px][j] (swizzled slots)
  const int t = threadIdx.x;
  const int tile = blockIdx.x;           // 0..47
  const int b = blockIdx.y;
  const int y0 = tile * 2;
  const int wave = t >> 6, lane = t & 63;
  const int lg = lane >> 4, lr = lane & 15;
  const int row = lane >> 5, xq = lane & 31, x0 = xq*4;
  const int y = y0 + row;
  const ushort_t* cf = (const ushort_t*)(ws + OFF_CORFLO) + (size_t)b*128*HWp;
  const float* wdq = (const float*)(ws + OFF_WDQ);
  const short8* wfr2 = (const short8*)(ws + OFF_WFRAG2);

  f32x4 acc[4][5];
#pragma unroll
  for (int g = 0; g < 4; g++)
#pragma unroll
    for (int mb = 0; mb < 5; mb++) acc[g][mb] = f32x4{0.f, 0.f, 0.f, 0.f};

  const bool has_up = (y > 0), has_dn = (y < 95);
  const bool has_l = (x0 > 0), has_r = (x0 < 124);

#define S2_STAGE(CB, BUF)                                                     \
  {                                                                           \
    _Pragma("unroll")                                                         \
    for (int i = 0; i < 8; i++) {                                             \
      int u = i*256 + t;                                                      \
      int x16 = u & 15, ry = (u >> 4) & 3, ch = u >> 6;                       \
      int yc = y0 - 1 + ry; yc = yc < 0 ? 0 : (yc > 95 ? 95 : yc);            \
      gload_lds16(cf + (size_t)((CB)*32 + ch)*HWp + yc*128 + x16*8,           \
                  &inb[BUF][u*8]);                                            \
    }                                                                         \
  }

  S2_STAGE(0, 0);

  for (int cb = 0; cb < 4; cb++) {
    const int cur = cb & 1;
    if (cb < 3) S2_STAGE(cb + 1, cur ^ 1);   // in flight under dw phase
    __syncthreads();   // inb[cur] ready (drain covered); prev-chunk readers done

    // ---- depthwise 3x3: 8 channels (oct = wave) x 4 px ----
    const ushort_t* inbc = inb[cur];
    float vv[4][8];
#pragma unroll
    for (int i = 0; i < 8; i++) {
      int ch = wave*8 + i;
      const float* w = wdq + (size_t)(cb*32 + ch)*9;
      float o0 = 0.f, o1 = 0.f, o2 = 0.f, o3 = 0.f;
      const ushort_t* rp = &inbc[(ch*4 + row)*128 + x0];
#pragma unroll
      for (int dy = 0; dy < 3; dy++) {
        if ((dy == 0 && !has_up) || (dy == 2 && !has_dn)) continue;
        const ushort_t* r = rp + dy*128;
        float c0 = bf2f(r[0]), c1 = bf2f(r[1]), c2 = bf2f(r[2]), c3 = bf2f(r[3]);
        float lf = has_l ? bf2f(r[-1]) : 0.f;
        float rt = has_r ? bf2f(r[4]) : 0.f;
        float w0 = w[dy*3], w1 = w[dy*3 + 1], w2 = w[dy*3 + 2];
        o0 += w0*lf + w1*c0 + w2*c1;
        o1 += w0*c0 + w1*c1 + w2*c2;
        o2 += w0*c1 + w1*c2 + w2*c3;
        o3 += w0*c2 + w1*c3 + w2*rt;
      }
      vv[0][i] = o0; vv[1][i] = o1; vv[2][i] = o2; vv[3][i] = o3;
    }
#pragma unroll
    for (int p = 0; p < 4; p++) {
      short8 pk;
#pragma unroll
      for (int i = 0; i < 8; i++) pk[i] = f2bf(vv[p][i]);
      *(short8*)&actc[swz(wave*256 + row*128 + x0 + p)*8] = pk;
    }
    __syncthreads();   // actc ready for all waves

    // ---- MFMA K-step for this chunk ----
    short8 wv[5];
#pragma unroll
    for (int mb = 0; mb < 5; mb++) wv[mb] = wfr2[(cb*5 + mb)*64 + lane];
#pragma unroll
    for (int g = 0; g < 4; g++) {
      int px = wave*64 + g*16 + lr;
      short8 aa = *(const short8*)&actc[swz(lg*256 + px)*8];
#pragma unroll
      for (int mb = 0; mb < 5; mb++)
        acc[g][mb] = __builtin_amdgcn_mfma_f32_16x16x32_bf16(wv[mb], aa, acc[g][mb], 0, 0, 0);
    }
  }

  // ---- epilogue: bias + relu, then flow concat ----
  const size_t pix0 = (size_t)y0 * 128;
#pragma unroll
  for (int g = 0; g < 4; g++) {
    int px = wave*64 + g*16 + lr;
    float* dst = out + ((size_t)b*82)*HWp + pix0 + px;
#pragma unroll
    for (int mb = 0; mb < 5; mb++)
#pragma unroll
      for (int r = 0; r < 4; r++) {
        int ch = mb*16 + lg*4 + r;
        dst[(size_t)ch*HWp] = fmaxf(acc[g][mb][r] + bp[ch], 0.f);
      }
  }
  {
    size_t p = pix0 + t;
    out[((size_t)b*82 + 80)*HWp + p] = flow[((size_t)b*2 + 0)*HWp + p];
    out[((size_t)b*82 + 81)*HWp + p] = flow[((size_t)b*2 + 1)*HWp + p];
  }
#undef S2_STAGE
}

// ---------------------------------------------------------------------------
extern "C" void kernel_launch(void* const* d_in, const int* in_sizes, int n_in,
                              void* d_out, int out_size, void* d_ws, size_t ws_size,
                              hipStream_t stream)
{
  const float* flow = (const float*)d_in[0];
  const float* corr = (const float*)d_in[1];
  const float* Wc1  = (const float*)d_in[2];
  const float* bc1  = (const float*)d_in[3];
  const float* Wf1  = (const float*)d_in[4];
  const float* bf1  = (const float*)d_in[5];
  const float* Wf2  = (const float*)d_in[6];
  const float* bf2  = (const float*)d_in[7];
  const float* Wd   = (const float*)d_in[8];
  const float* Wp   = (const float*)d_in[9];
  const float* bp   = (const float*)d_in[10];
  char* ws = (char*)d_ws;
  float* out = (float*)d_out;

  hipLaunchKernelGGL(quant_pack, dim3(5), dim3(1024), 0, stream,
                     Wc1, Wf1, Wf2, Wd, Wp, ws);
  hipLaunchKernelGGL(stage1_mfma, dim3(1536), dim3(256), 0, stream,
                     corr, bc1, ws);
  hipLaunchKernelGGL(flow_path, dim3(768), dim3(256), 0, stream,
                     flow, bf1, bf2, ws);
  hipLaunchKernelGGL(stage2_mfma, dim3(48, 16), dim3(256), 0, stream,
                     bp, flow, ws, out);
}